// Round 4
// baseline (1196.121 us; speedup 1.0000x reference)
//
#include <hip/hip_runtime.h>
#include <hip/hip_bf16.h>

typedef __attribute__((ext_vector_type(8))) short bf16x8;
typedef __attribute__((ext_vector_type(4))) float f32x4;

__device__ __forceinline__ unsigned short f2bf(float f) {
    unsigned u = __builtin_bit_cast(unsigned, f);
    u += 0x7FFFu + ((u >> 16) & 1u);   // RNE
    return (unsigned short)(u >> 16);
}

// async global->LDS, 16B per lane: LDS dest = wave-uniform base + lane*16.
__device__ __forceinline__ void async16(const void* g, void* l) {
    __builtin_amdgcn_global_load_lds(
        (const __attribute__((address_space(1))) unsigned int*)g,
        (__attribute__((address_space(3))) unsigned int*)l, 16, 0, 0);
}

__global__ void cvt_f32_bf16(const float* __restrict__ x, unsigned short* __restrict__ y, int n4) {
    const int stride = gridDim.x * blockDim.x;
    for (int i = blockIdx.x * blockDim.x + threadIdx.x; i < n4; i += stride) {
        const float4 v = ((const float4*)x)[i];
        ushort4 o;
        o.x = f2bf(v.x); o.y = f2bf(v.y); o.z = f2bf(v.z); o.w = f2bf(v.w);
        ((ushort4*)y)[i] = o;
    }
}

// C[M,N] = A[M,K] @ Bt[N,K]^T + bias. m97 structure with BK=64:
// identity-chunk LDS (chunk c: m-tile c>>1, k-group c&1; lane i owns bytes
// [16i,16i+16)), 8 async16/thread/iter, 32 MFMA/iter, 32 KB LDS, 64 iters.
template <bool OUT_F32>
__global__ __launch_bounds__(256) void gemm_bf16(
    const unsigned short* __restrict__ A, const unsigned short* __restrict__ Bt,
    const float* __restrict__ bias, void* __restrict__ Cp, int N, int K)
{
    __shared__ __align__(16) unsigned short lds[16384];   // A [0,8192), B [8192,16384)
    const int tid = threadIdx.x;
    const int wave = tid >> 6, lane = tid & 63;
    const int l16 = lane & 15, quad = lane >> 4;
    const int m0 = blockIdx.y * 128, n0 = blockIdx.x * 128;
    const int wm4 = (wave & 1) * 4, wn4 = (wave >> 1) * 4;

    f32x4 acc[4][4] = {};

    const unsigned short* gA[4];
    const unsigned short* gB[4];
    unsigned short* lA[4];
    unsigned short* lB[4];
#pragma unroll
    for (int t = 0; t < 4; ++t) {
        const int c = wave * 4 + t;          // chunk 0..15
        const int mt = c >> 1, kg = c & 1;
        gA[t] = A  + (size_t)(m0 + mt * 16 + l16) * K + kg * 32 + quad * 8;
        gB[t] = Bt + (size_t)(n0 + mt * 16 + l16) * K + kg * 32 + quad * 8;
        lA[t] = &lds[c * 512];
        lB[t] = &lds[8192 + c * 512];
    }

    for (int k0 = 0; k0 < K; k0 += 64) {
        __syncthreads();
#pragma unroll
        for (int t = 0; t < 4; ++t) {
            async16(gA[t] + k0, lA[t]);
            async16(gB[t] + k0, lB[t]);
        }
        __syncthreads();

#pragma unroll
        for (int kg = 0; kg < 2; ++kg) {
            bf16x8 af[4], bfq[4];
#pragma unroll
            for (int i = 0; i < 4; ++i)
                af[i] = *(const bf16x8*)&lds[((wm4 + i) * 2 + kg) * 512 + lane * 8];
#pragma unroll
            for (int j = 0; j < 4; ++j)
                bfq[j] = *(const bf16x8*)&lds[8192 + ((wn4 + j) * 2 + kg) * 512 + lane * 8];
#pragma unroll
            for (int i = 0; i < 4; ++i)
#pragma unroll
                for (int j = 0; j < 4; ++j)
                    acc[i][j] = __builtin_amdgcn_mfma_f32_16x16x32_bf16(af[i], bfq[j], acc[i][j], 0, 0, 0);
        }
    }

#pragma unroll
    for (int j = 0; j < 4; ++j) {
        const int n = n0 + (wn4 + j) * 16 + l16;
        const float bv = bias[n];
#pragma unroll
        for (int i = 0; i < 4; ++i) {
            const int mb = m0 + (wm4 + i) * 16 + quad * 4;
#pragma unroll
            for (int r = 0; r < 4; ++r) {
                const float v = acc[i][j][r] + bv;
                if constexpr (OUT_F32) ((float*)Cp)[(size_t)(mb + r) * N + n] = v;
                else ((unsigned short*)Cp)[(size_t)(mb + r) * N + n] = f2bf(v);
            }
        }
    }
}

// Fused QKV projection, BK=64. Wcat = [Wq;Wk;Wv] rows (4352 x 4096 bf16).
// grid = (34, 32). n0<4096 -> Q; n0==4096 -> K; n0==4224 -> V transposed.
__global__ __launch_bounds__(256) void gemm_qkv(
    const unsigned short* __restrict__ A, const unsigned short* __restrict__ Wcat,
    const float* __restrict__ bq, const float* __restrict__ bk, const float* __restrict__ bv,
    unsigned short* __restrict__ q_out, unsigned short* __restrict__ k_out,
    unsigned short* __restrict__ vT)
{
    constexpr int K = 4096;
    __shared__ __align__(16) unsigned short lds[16384];
    const int tid = threadIdx.x;
    const int wave = tid >> 6, lane = tid & 63;
    const int l16 = lane & 15, quad = lane >> 4;
    const int m0 = blockIdx.y * 128, n0 = blockIdx.x * 128;
    const int wm4 = (wave & 1) * 4, wn4 = (wave >> 1) * 4;

    f32x4 acc[4][4] = {};

    const unsigned short* gA[4];
    const unsigned short* gB[4];
    unsigned short* lA[4];
    unsigned short* lB[4];
#pragma unroll
    for (int t = 0; t < 4; ++t) {
        const int c = wave * 4 + t;
        const int mt = c >> 1, kg = c & 1;
        gA[t] = A    + (size_t)(m0 + mt * 16 + l16) * K + kg * 32 + quad * 8;
        gB[t] = Wcat + (size_t)(n0 + mt * 16 + l16) * K + kg * 32 + quad * 8;
        lA[t] = &lds[c * 512];
        lB[t] = &lds[8192 + c * 512];
    }

    for (int k0 = 0; k0 < K; k0 += 64) {
        __syncthreads();
#pragma unroll
        for (int t = 0; t < 4; ++t) {
            async16(gA[t] + k0, lA[t]);
            async16(gB[t] + k0, lB[t]);
        }
        __syncthreads();

#pragma unroll
        for (int kg = 0; kg < 2; ++kg) {
            bf16x8 af[4], bfq[4];
#pragma unroll
            for (int i = 0; i < 4; ++i)
                af[i] = *(const bf16x8*)&lds[((wm4 + i) * 2 + kg) * 512 + lane * 8];
#pragma unroll
            for (int j = 0; j < 4; ++j)
                bfq[j] = *(const bf16x8*)&lds[8192 + ((wn4 + j) * 2 + kg) * 512 + lane * 8];
#pragma unroll
            for (int i = 0; i < 4; ++i)
#pragma unroll
                for (int j = 0; j < 4; ++j)
                    acc[i][j] = __builtin_amdgcn_mfma_f32_16x16x32_bf16(af[i], bfq[j], acc[i][j], 0, 0, 0);
        }
    }

    if (n0 < 4096) {                 // Q region
#pragma unroll
        for (int j = 0; j < 4; ++j) {
            const int n = n0 + (wn4 + j) * 16 + l16;
            const float bb = bq[n];
#pragma unroll
            for (int i = 0; i < 4; ++i) {
                const int mb = m0 + (wm4 + i) * 16 + quad * 4;
#pragma unroll
                for (int r = 0; r < 4; ++r)
                    q_out[(size_t)(mb + r) * 4096 + n] = f2bf(acc[i][j][r] + bb);
            }
        }
    } else if (n0 == 4096) {         // K region
#pragma unroll
        for (int j = 0; j < 4; ++j) {
            const int d = (wn4 + j) * 16 + l16;
            const float bb = bk[d];
#pragma unroll
            for (int i = 0; i < 4; ++i) {
                const int mb = m0 + (wm4 + i) * 16 + quad * 4;
#pragma unroll
                for (int r = 0; r < 4; ++r)
                    k_out[(size_t)(mb + r) * 128 + d] = f2bf(acc[i][j][r] + bb);
            }
        }
    } else {                         // V region -> transposed vT[b][d][s]
#pragma unroll
        for (int j = 0; j < 4; ++j) {
            const int d = (wn4 + j) * 16 + l16;
            const float bb = bv[d];
#pragma unroll
            for (int i = 0; i < 4; ++i) {
                const int mb = m0 + (wm4 + i) * 16 + quad * 4;
                ushort4 o;
                o.x = f2bf(acc[i][j][0] + bb);
                o.y = f2bf(acc[i][j][1] + bb);
                o.z = f2bf(acc[i][j][2] + bb);
                o.w = f2bf(acc[i][j][3] + bb);
                *(ushort4*)(vT + (size_t)((mb >> 11) * 128 + d) * 2048 + (mb & 2047)) = o;
            }
        }
    }
}

// Flash MQA, fixed-max softmax. Unchanged from round 3 (isolating the GEMM
// change; attn counters land in next round's top-5).
__global__ __launch_bounds__(256) void attn_mqa(
    const unsigned short* __restrict__ Q,
    const unsigned short* __restrict__ Kb,
    const unsigned short* __restrict__ vT,
    unsigned short* __restrict__ scr)
{
    constexpr int S = 2048, D = 128, H = 4096;
    constexpr float CSC = 0.0883883476483184f * 1.4426950408889634f;  // 1/sqrt(D)*log2(e)

    __shared__ __align__(16) unsigned short lds[25600];
    const int tid = threadIdx.x;
    const int w = tid >> 6, lane = tid & 63;
    const int l16 = lane & 15, quad = lane >> 4;
    const int qb = blockIdx.x & 15;
    const int h  = (blockIdx.x >> 4) & 31;
    const int b  = blockIdx.x >> 9;
    const int q0 = qb * 128;

    bf16x8 qf[2][4];
#pragma unroll
    for (int mi = 0; mi < 2; ++mi)
#pragma unroll
        for (int ks = 0; ks < 4; ++ks)
            qf[mi][ks] = *(const bf16x8*)(Q + (size_t)(b * S + q0 + w * 32 + mi * 16 + l16) * H
                                            + h * D + ks * 32 + quad * 8);

    f32x4 Oa[2][8] = {};
    float l_run[2][4] = {};

    const unsigned short* gK = Kb + (size_t)(b * S + l16) * D + quad * 8;
    const unsigned short* gV = vT + (size_t)(b * 128 + l16) * 2048 + quad * 8;

    for (int kv0 = 0; kv0 < S; kv0 += 64) {
        __syncthreads();
#pragma unroll
        for (int t = 0; t < 4; ++t) {
            const int c = w * 4 + t;
            const int ct = c >> 2, ks = c & 3;
            async16(gK + (size_t)(kv0 + ct * 16) * D + ks * 32, &lds[c * 512]);
            const int nt = c >> 1, kk = c & 1;
            async16(gV + (size_t)(nt * 16) * 2048 + kv0 + kk * 32, &lds[8192 + c * 512]);
        }
        __syncthreads();

        f32x4 sf[2][4] = {};
#pragma unroll
        for (int ct = 0; ct < 4; ++ct)
#pragma unroll
            for (int ks = 0; ks < 4; ++ks) {
                const bf16x8 kf = *(const bf16x8*)&lds[(ct * 4 + ks) * 512 + lane * 8];
#pragma unroll
                for (int mi = 0; mi < 2; ++mi)
                    sf[mi][ct] = __builtin_amdgcn_mfma_f32_16x16x32_bf16(qf[mi][ks], kf, sf[mi][ct], 0, 0, 0);
            }

#pragma unroll
        for (int mi = 0; mi < 2; ++mi)
#pragma unroll
            for (int ct = 0; ct < 4; ++ct)
#pragma unroll
                for (int i = 0; i < 4; ++i) {
                    const float p = exp2f(sf[mi][ct][i] * CSC);
                    l_run[mi][i] += p;
                    lds[16384 + (w * 2 + mi) * 1152 + (quad * 4 + i) * 72 + ct * 16 + l16] = f2bf(p);
                }
        asm volatile("s_waitcnt lgkmcnt(0)" ::: "memory");

        bf16x8 ap[2][2];
#pragma unroll
        for (int mi = 0; mi < 2; ++mi)
#pragma unroll
            for (int kk = 0; kk < 2; ++kk)
                ap[mi][kk] = *(const bf16x8*)&lds[16384 + (w * 2 + mi) * 1152 + l16 * 72 + kk * 32 + quad * 8];
#pragma unroll
        for (int nt = 0; nt < 8; ++nt)
#pragma unroll
            for (int kk = 0; kk < 2; ++kk) {
                const bf16x8 vf = *(const bf16x8*)&lds[8192 + (nt * 2 + kk) * 512 + lane * 8];
#pragma unroll
                for (int mi = 0; mi < 2; ++mi)
                    Oa[mi][nt] = __builtin_amdgcn_mfma_f32_16x16x32_bf16(ap[mi][kk], vf, Oa[mi][nt], 0, 0, 0);
            }
    }

    float inv[2][4];
#pragma unroll
    for (int mi = 0; mi < 2; ++mi)
#pragma unroll
        for (int i = 0; i < 4; ++i) {
            float l = l_run[mi][i];
            l += __shfl_xor(l, 1);
            l += __shfl_xor(l, 2);
            l += __shfl_xor(l, 4);
            l += __shfl_xor(l, 8);
            inv[mi][i] = 1.f / l;
        }

    __syncthreads();
#pragma unroll
    for (int mi = 0; mi < 2; ++mi)
#pragma unroll
        for (int nt = 0; nt < 8; ++nt)
#pragma unroll
            for (int i = 0; i < 4; ++i)
                lds[(nt * 16 + l16) * 136 + w * 32 + mi * 16 + quad * 4 + i] =
                    f2bf(Oa[mi][nt][i] * inv[mi][i]);
    __syncthreads();

    const int d = tid >> 1, qh = tid & 1;
    unsigned short* op = scr + (size_t)(b * S + h * 64 + (d >> 1)) * H + (d & 1) * 2048 + q0 + qh * 64;
#pragma unroll
    for (int j = 0; j < 8; ++j)
        *(int4*)(op + j * 8) = *(const int4*)&lds[d * 136 + qh * 64 + j * 8];
}

extern "C" void kernel_launch(void* const* d_in, const int* in_sizes, int n_in,
                              void* d_out, int out_size, void* d_ws, size_t ws_size,
                              hipStream_t stream) {
    (void)in_sizes; (void)n_in; (void)out_size; (void)ws_size;
    const float* hidden = (const float*)d_in[0];
    const float* Wq = (const float*)d_in[1];
    const float* bq = (const float*)d_in[2];
    const float* Wk = (const float*)d_in[3];
    const float* bk = (const float*)d_in[4];
    const float* Wv = (const float*)d_in[5];
    const float* bv = (const float*)d_in[6];
    const float* Wo = (const float*)d_in[7];
    const float* bo = (const float*)d_in[8];

    char* ws = (char*)d_ws;
    const size_t MB = 1048576;
    unsigned short* hb   = (unsigned short*)(ws);                 // 32 MB; scr aliases (hb dead after QKV)
    unsigned short* scr  = hb;
    unsigned short* Wcat = (unsigned short*)(ws + 32 * MB);       // 36 MB: [Wq;Wk;Wv]; Wob aliases after QKV
    unsigned short* Wob  = Wcat;
    unsigned short* q_b  = (unsigned short*)(ws + 68 * MB);       // 32 MB
    unsigned short* k_b  = (unsigned short*)(ws + 100 * MB);      // 1 MB
    unsigned short* vT   = (unsigned short*)(ws + 101 * MB);      // 1 MB

    cvt_f32_bf16<<<1024, 256, 0, stream>>>(hidden, hb, 16777216 / 4);
    cvt_f32_bf16<<<1024, 256, 0, stream>>>(Wq, Wcat, 16777216 / 4);
    cvt_f32_bf16<<<256, 256, 0, stream>>>(Wk, Wcat + 16777216, 524288 / 4);
    cvt_f32_bf16<<<256, 256, 0, stream>>>(Wv, Wcat + 17301504, 524288 / 4);

    gemm_qkv<<<dim3(34, 32), 256, 0, stream>>>(hb, Wcat, bq, bk, bv, q_b, k_b, vT);
    cvt_f32_bf16<<<1024, 256, 0, stream>>>(Wo, Wob, 16777216 / 4);
    attn_mqa<<<1024, 256, 0, stream>>>(q_b, k_b, vT, scr);
    gemm_bf16<true><<<dim3(32, 32), 256, 0, stream>>>(scr, Wob, bo, (float*)d_out, 4096, 4096);
}